// Round 1
// baseline (538.902 us; speedup 1.0000x reference)
//
#include <hip/hip_runtime.h>

// ============================================================================
// InteractionLayer: Q/K/V projections (bf16 MFMA) + fused flash attention.
// All MFMA = v_mfma_f32_32x32x16_bf16.
//   a-operand: lane l holds A[row=l&31][k=(l>>5)*8 + j], j=0..7 (k-contiguous)
//   b-operand: lane l holds B[k=(l>>5)*8 + j][col=l&31]  (i.e. B^T row-major)
//   C/D:       col=lane&31, row=(reg&3)+8*(reg>>2)+4*(lane>>5)   [m74/m101]
// ============================================================================

typedef __attribute__((ext_vector_type(8)))  short short8;
typedef __attribute__((ext_vector_type(4)))  short short4v;
typedef __attribute__((ext_vector_type(16))) float f32x16;
typedef __attribute__((ext_vector_type(4)))  float float4v;

#define LOG2E 1.4426950408889634f

__device__ __forceinline__ short f2bf(float x){
  unsigned int u = __float_as_uint(x);
  u = (u + 0x7FFFu + ((u >> 16) & 1u)) >> 16;   // RNE f32->bf16 (finite inputs)
  return (short)u;
}

// ---------------- weight transpose + bf16 convert ----------------
// in: [K][512] f32 row-major ; out: [512][K] bf16 row-major. Coalesced reads.
__global__ __launch_bounds__(256) void transpose_cvt(
    const float* __restrict__ in, short* __restrict__ out, int kbits)
{
  int idx = blockIdx.x * 256 + threadIdx.x;
  int n = idx & 511;
  int k = idx >> 9;
  out[((size_t)n << kbits) + k] = f2bf(in[idx]);
}

// ---------------- projection GEMM ----------------
// C[16384,512] = A[16384,K]*W[K,512] + bias, then *alpha.
// A f32 row-major (converted to bf16 while staging), WT bf16 [512][K].
// TRANS=0: C row-major bf16 [16384][512].  TRANS=1: C^T per batch [4][512][4096].
template<int TRANS>
__global__ __launch_bounds__(256, 2) void proj_gemm(
    const float* __restrict__ A, const short* __restrict__ WT,
    const float* __restrict__ bias, short* __restrict__ C,
    int K, float alpha)
{
  __shared__ short As[128*72];   // stride 72 bf16 = 144B -> 4-way max on b128 reads
  __shared__ short Bs[128*72];
  const int tid = threadIdx.x;
  const int wid = tid >> 6, lane = tid & 63;
  const int lo = lane & 31, hi = lane >> 5;
  const int wm = wid >> 1, wn = wid & 1;
  const int bm = blockIdx.x, bn = blockIdx.y;

  f32x16 acc[2][2];
  #pragma unroll
  for (int i=0;i<2;i++)
    #pragma unroll
    for (int j=0;j<2;j++)
      #pragma unroll
      for (int r=0;r<16;r++) acc[i][j][r] = 0.0f;

  const int srow = tid >> 3, sslot = tid & 7;
  for (int k0 = 0; k0 < K; k0 += 64) {
    #pragma unroll
    for (int i=0;i<4;i++){
      const int row = srow + 32*i;
      const float4v* src = (const float4v*)&A[(size_t)(bm*128+row)*K + k0 + sslot*8];
      float4v f0 = src[0], f1 = src[1];
      short8 v;
      v[0]=f2bf(f0[0]); v[1]=f2bf(f0[1]); v[2]=f2bf(f0[2]); v[3]=f2bf(f0[3]);
      v[4]=f2bf(f1[0]); v[5]=f2bf(f1[1]); v[6]=f2bf(f1[2]); v[7]=f2bf(f1[3]);
      *(short8*)&As[row*72 + sslot*8] = v;
      *(short8*)&Bs[row*72 + sslot*8] =
          *(const short8*)&WT[(size_t)(bn*128+row)*K + k0 + sslot*8];
    }
    __syncthreads();
    #pragma unroll
    for (int dc=0; dc<4; dc++){
      short8 af[2], bfr[2];
      #pragma unroll
      for (int mt=0;mt<2;mt++)
        af[mt] = *(const short8*)&As[(wm*64+mt*32+lo)*72 + dc*16 + hi*8];
      #pragma unroll
      for (int nt=0;nt<2;nt++)
        bfr[nt] = *(const short8*)&Bs[(wn*64+nt*32+lo)*72 + dc*16 + hi*8];
      #pragma unroll
      for (int mt=0;mt<2;mt++)
        #pragma unroll
        for (int nt=0;nt<2;nt++)
          acc[mt][nt] = __builtin_amdgcn_mfma_f32_32x32x16_bf16(af[mt], bfr[nt], acc[mt][nt], 0, 0, 0);
    }
    __syncthreads();
  }

  #pragma unroll
  for (int nt=0;nt<2;nt++){
    const int col = bn*128 + wn*64 + nt*32 + lo;
    const float bv = bias[col];
    #pragma unroll
    for (int mt=0;mt<2;mt++){
      const int grow0 = bm*128 + wm*64 + mt*32;
      if (TRANS){
        const int bb = grow0 >> 12;        // batch (blocks never straddle batches)
        const int tb = grow0 & 4095;
        #pragma unroll
        for (int g=0; g<4; g++){           // regs 4g..4g+3 are consecutive rows (t)
          short4v pv;
          #pragma unroll
          for (int j=0;j<4;j++)
            pv[j] = f2bf((acc[mt][nt][4*g+j] + bv)*alpha);
          *(short4v*)&C[((size_t)bb*512 + col)*4096 + tb + g*8 + hi*4] = pv;
        }
      } else {
        #pragma unroll
        for (int r=0;r<16;r++){
          const int grow = grow0 + (r&3) + 8*(r>>2) + 4*hi;
          C[(size_t)grow*512 + col] = f2bf((acc[mt][nt][r] + bv)*alpha);
        }
      }
    }
  }
}

// ---------------- fused flash attention ----------------
// 256 blocks (b, q-tile of 64) x 512 threads (8 waves).
// S-phase: wave w=(quad=w>>1, qc=w&1): S^T[kv=quad*128+c*32..][q=qc*32..]
//          = sum_d mfma(K-frag(global), Q-frag(LDS)).
// softmax: per-lane (col q fixed) over 64 regs + shfl_xor(32) + LDS cross-wave.
// PV: wave w = d-slice 64*w: O^T[d][q] += mfma(V^T-frag(global), P-frag(LDS)).
__global__ __launch_bounds__(512, 2) void attn_fwd(
    const short* __restrict__ Qg, const short* __restrict__ Kg,
    const short* __restrict__ VT, float* __restrict__ out)
{
  extern __shared__ char smem[];
  short* q_lds    = (short*)smem;                    // [64][520] bf16
  short* p_lds    = (short*)(smem + 64*520*2);       // [64][520] bf16
  float* pmax_lds = (float*)(smem + 2*64*520*2);     // [8][32]
  float* lsum_lds = pmax_lds + 8*32;                 // [8][32]

  const int tid = threadIdx.x;
  const int w = tid >> 6, lane = tid & 63;
  const int lo = lane & 31, hi = lane >> 5;
  const int quad = w >> 1, sqc = w & 1;
  const int bq = blockIdx.x;
  const int b = bq >> 6, qt = bq & 63;
  const size_t qrow0 = ((size_t)b << 12) + (size_t)qt*64;

  { // stage Q tile (pre-scaled in projection): 64 rows x 512
    const int qr = tid >> 6, sl = tid & 63;
    #pragma unroll
    for (int i=0;i<8;i++){
      const int q = qr + 8*i;
      *(short8*)&q_lds[q*520 + sl*8] =
          *(const short8*)&Qg[(qrow0 + q)*512 + sl*8];
    }
  }

  f32x16 oacc[2][2];   // [dtile][qc]
  #pragma unroll
  for (int i=0;i<2;i++)
    #pragma unroll
    for (int j=0;j<2;j++)
      #pragma unroll
      for (int r=0;r<16;r++) oacc[i][j][r]=0.f;
  float m_run[2] = {-INFINITY, -INFINITY};
  float l_run[2] = {0.f, 0.f};
  __syncthreads();

  for (int t0 = 0; t0 < 4096; t0 += 512) {
    // ---- S phase ----
    f32x16 sacc[4];
    #pragma unroll
    for (int c=0;c<4;c++)
      #pragma unroll
      for (int r=0;r<16;r++) sacc[c][r]=0.f;

    const short* kbase = &Kg[((size_t)b*4096 + t0 + quad*128 + lo)*512];
    const short* qrow  = &q_lds[(sqc*32+lo)*520];
    #pragma unroll 4
    for (int dc=0; dc<32; dc++){
      const short8 bq8 = *(const short8*)&qrow[dc*16 + hi*8];
      #pragma unroll
      for (int c=0;c<4;c++){
        const short8 af = *(const short8*)&kbase[(size_t)c*32*512 + dc*16 + hi*8];
        sacc[c] = __builtin_amdgcn_mfma_f32_32x32x16_bf16(af, bq8, sacc[c], 0, 0, 0);
      }
    }

    // ---- online softmax ----
    float px = -INFINITY;
    #pragma unroll
    for (int c=0;c<4;c++)
      #pragma unroll
      for (int r=0;r<16;r++) px = fmaxf(px, sacc[c][r]);
    px = fmaxf(px, __shfl_xor(px, 32));
    if (hi == 0) pmax_lds[w*32 + lo] = px;
    __syncthreads();                         // B1

    float m_new[2], resc[2];
    #pragma unroll
    for (int qc=0; qc<2; qc++){
      float mm = m_run[qc];
      #pragma unroll
      for (int qd=0; qd<4; qd++) mm = fmaxf(mm, pmax_lds[(qd*2+qc)*32 + lo]);
      m_new[qc] = mm;
      resc[qc] = exp2f((m_run[qc] - mm) * LOG2E);
      m_run[qc] = mm;
    }
    #pragma unroll
    for (int dt=0;dt<2;dt++)
      #pragma unroll
      for (int qc=0;qc<2;qc++)
        #pragma unroll
        for (int r=0;r<16;r++) oacc[dt][qc][r] *= resc[qc];

    float ls = 0.f;
    const float mts = m_new[sqc];
    #pragma unroll
    for (int c=0;c<4;c++){
      #pragma unroll
      for (int g=0; g<4; g++){               // regs 4g..4g+3 = consecutive kv
        short4v pv;
        #pragma unroll
        for (int j=0;j<4;j++){
          const float p = exp2f((sacc[c][4*g+j] - mts) * LOG2E);
          ls += p;
          pv[j] = f2bf(p);
        }
        *(short4v*)&p_lds[(sqc*32+lo)*520 + quad*128 + c*32 + g*8 + hi*4] = pv;
      }
    }
    ls += __shfl_xor(ls, 32);
    if (hi == 0) lsum_lds[w*32 + lo] = ls;
    __syncthreads();                         // B2

    #pragma unroll
    for (int qc=0; qc<2; qc++){
      float s = 0.f;
      #pragma unroll
      for (int qd=0; qd<4; qd++) s += lsum_lds[(qd*2+qc)*32 + lo];
      l_run[qc] = l_run[qc]*resc[qc] + s;
    }

    // ---- PV phase: wave owns d-slice [64w, 64w+64) ----
    const short* vbase = &VT[((size_t)b*512 + w*64 + lo)*4096 + t0];
    #pragma unroll 4
    for (int kc=0; kc<32; kc++){
      const short8 pf0 = *(const short8*)&p_lds[lo*520      + kc*16 + hi*8];
      const short8 pf1 = *(const short8*)&p_lds[(32+lo)*520 + kc*16 + hi*8];
      #pragma unroll
      for (int dt=0; dt<2; dt++){
        const short8 vf = *(const short8*)&vbase[(size_t)dt*32*4096 + kc*16 + hi*8];
        oacc[dt][0] = __builtin_amdgcn_mfma_f32_32x32x16_bf16(vf, pf0, oacc[dt][0], 0, 0, 0);
        oacc[dt][1] = __builtin_amdgcn_mfma_f32_32x32x16_bf16(vf, pf1, oacc[dt][1], 0, 0, 0);
      }
    }
  }

  // ---- epilogue: out[q][d] = O^T[d][q] / l ----
  #pragma unroll
  for (int qc=0;qc<2;qc++){
    const float inv = 1.0f / l_run[qc];
    const size_t row = qrow0 + qc*32 + lo;
    #pragma unroll
    for (int dt=0;dt<2;dt++){
      #pragma unroll
      for (int g=0;g<4;g++){
        float4v ov;
        #pragma unroll
        for (int j=0;j<4;j++) ov[j] = oacc[dt][qc][4*g+j]*inv;
        *(float4v*)&out[row*512 + w*64 + dt*32 + g*8 + hi*4] = ov;
      }
    }
  }
}

extern "C" void kernel_launch(void* const* d_in, const int* in_sizes, int n_in,
                              void* d_out, int out_size, void* d_ws, size_t ws_size,
                              hipStream_t stream)
{
  const float* m_states = (const float*)d_in[0];
  const float* f_k      = (const float*)d_in[1];
  const float* f_v      = (const float*)d_in[2];
  const float* W_q      = (const float*)d_in[3];
  const float* b_q      = (const float*)d_in[4];
  const float* W_k      = (const float*)d_in[5];
  const float* b_k      = (const float*)d_in[6];
  const float* W_v      = (const float*)d_in[7];
  const float* b_v      = (const float*)d_in[8];
  float* out = (float*)d_out;

  // workspace: WqT 1MB | WkT 0.5MB | WvT 0.5MB | Qbf16 16MB | Kbf16 16MB | V^T 16MB
  char* ws = (char*)d_ws;
  short* WqT = (short*)(ws);
  short* WkT = (short*)(ws + 1048576);
  short* WvT = (short*)(ws + 1048576 + 524288);
  short* Qb  = (short*)(ws + 2097152);
  short* Kb  = Qb + (size_t)16384*512;
  short* VTw = Kb + (size_t)16384*512;

  transpose_cvt<<<2048, 256, 0, stream>>>(W_q, WqT, 10);
  transpose_cvt<<<1024, 256, 0, stream>>>(W_k, WkT, 9);
  transpose_cvt<<<1024, 256, 0, stream>>>(W_v, WvT, 9);

  const float scale = 0.044194173824159216f;   // 1/sqrt(512), folded into Q
  proj_gemm<0><<<dim3(128,4), 256, 0, stream>>>(m_states, WqT, b_q, Qb, 1024, scale);
  proj_gemm<0><<<dim3(128,4), 256, 0, stream>>>(f_k,      WkT, b_k, Kb,  512, 1.0f);
  proj_gemm<1><<<dim3(128,4), 256, 0, stream>>>(f_v,      WvT, b_v, VTw, 512, 1.0f);

  attn_fwd<<<256, 512, 135168, stream>>>(Qb, Kb, VTw, out);
}

// Round 2
// 329.345 us; speedup vs baseline: 1.6363x; 1.6363x over previous
//
#include <hip/hip_runtime.h>

// ============================================================================
// InteractionLayer: Q/K/V projections (bf16 MFMA) + fused flash attention.
// All MFMA = v_mfma_f32_32x32x16_bf16.
//   a-operand: lane l holds A[row=l&31][k=(l>>5)*8 + j], j=0..7 (k-contiguous)
//   b-operand: lane l holds B[k=(l>>5)*8 + j][col=l&31]
//   C/D:       col=lane&31, row=(reg&3)+8*(reg>>2)+4*(lane>>5)   [m74/m101]
// Attention v2: K/V staged through LDS ring (global_load_lds w/ pre-swizzled
// source), Q resident in swizzled LDS, P^T in swizzled LDS. KVBLK=128.
// ============================================================================

typedef __attribute__((ext_vector_type(8)))  short short8;
typedef __attribute__((ext_vector_type(4)))  short short4v;
typedef __attribute__((ext_vector_type(16))) float f32x16;
typedef __attribute__((ext_vector_type(4)))  float float4v;

#define LOG2E 1.4426950408889634f

__device__ __forceinline__ short f2bf(float x){
  unsigned int u = __float_as_uint(x);
  u = (u + 0x7FFFu + ((u >> 16) & 1u)) >> 16;   // RNE f32->bf16 (finite inputs)
  return (short)u;
}

typedef const __attribute__((address_space(1))) unsigned int guint_t;
typedef __attribute__((address_space(3))) unsigned int luint_t;
__device__ __forceinline__ void gl_lds16(const void* g, void* l){
  __builtin_amdgcn_global_load_lds((guint_t*)g, (luint_t*)l, 16, 0, 0);
}

// ---------------- weight transpose + bf16 convert ----------------
__global__ __launch_bounds__(256) void transpose_cvt(
    const float* __restrict__ in, short* __restrict__ out, int kbits)
{
  int idx = blockIdx.x * 256 + threadIdx.x;
  int n = idx & 511;
  int k = idx >> 9;
  out[((size_t)n << kbits) + k] = f2bf(in[idx]);
}

// ---------------- projection GEMM ----------------
// C[16384,512] = A[16384,K]*W[K,512] + bias, then *alpha.
// TRANS=0: C row-major bf16 [16384][512].
// TRANS=1: V^T t-block-tiled: [4 b][128 tblk][512 d][32 t]  (32KB slabs)
template<int TRANS>
__global__ __launch_bounds__(256, 2) void proj_gemm(
    const float* __restrict__ A, const short* __restrict__ WT,
    const float* __restrict__ bias, short* __restrict__ C,
    int K, float alpha)
{
  __shared__ short As[128*72];
  __shared__ short Bs[128*72];
  const int tid = threadIdx.x;
  const int wid = tid >> 6, lane = tid & 63;
  const int lo = lane & 31, hi = lane >> 5;
  const int wm = wid >> 1, wn = wid & 1;
  const int bm = blockIdx.x, bn = blockIdx.y;

  f32x16 acc[2][2];
  #pragma unroll
  for (int i=0;i<2;i++)
    #pragma unroll
    for (int j=0;j<2;j++)
      #pragma unroll
      for (int r=0;r<16;r++) acc[i][j][r] = 0.0f;

  const int srow = tid >> 3, sslot = tid & 7;
  for (int k0 = 0; k0 < K; k0 += 64) {
    #pragma unroll
    for (int i=0;i<4;i++){
      const int row = srow + 32*i;
      const float4v* src = (const float4v*)&A[(size_t)(bm*128+row)*K + k0 + sslot*8];
      float4v f0 = src[0], f1 = src[1];
      short8 v;
      v[0]=f2bf(f0[0]); v[1]=f2bf(f0[1]); v[2]=f2bf(f0[2]); v[3]=f2bf(f0[3]);
      v[4]=f2bf(f1[0]); v[5]=f2bf(f1[1]); v[6]=f2bf(f1[2]); v[7]=f2bf(f1[3]);
      *(short8*)&As[row*72 + sslot*8] = v;
      *(short8*)&Bs[row*72 + sslot*8] =
          *(const short8*)&WT[(size_t)(bn*128+row)*K + k0 + sslot*8];
    }
    __syncthreads();
    #pragma unroll
    for (int dc=0; dc<4; dc++){
      short8 af[2], bfr[2];
      #pragma unroll
      for (int mt=0;mt<2;mt++)
        af[mt] = *(const short8*)&As[(wm*64+mt*32+lo)*72 + dc*16 + hi*8];
      #pragma unroll
      for (int nt=0;nt<2;nt++)
        bfr[nt] = *(const short8*)&Bs[(wn*64+nt*32+lo)*72 + dc*16 + hi*8];
      #pragma unroll
      for (int mt=0;mt<2;mt++)
        #pragma unroll
        for (int nt=0;nt<2;nt++)
          acc[mt][nt] = __builtin_amdgcn_mfma_f32_32x32x16_bf16(af[mt], bfr[nt], acc[mt][nt], 0, 0, 0);
    }
    __syncthreads();
  }

  #pragma unroll
  for (int nt=0;nt<2;nt++){
    const int col = bn*128 + wn*64 + nt*32 + lo;
    const float bv = bias[col];
    #pragma unroll
    for (int mt=0;mt<2;mt++){
      const int grow0 = bm*128 + wm*64 + mt*32;
      if (TRANS){
        const int bb = grow0 >> 12;
        const int tb = grow0 & 4095;          // multiple of 32
        const size_t base = ((size_t)(bb*128 + (tb>>5))*512 + col)*32;
        #pragma unroll
        for (int g=0; g<4; g++){
          short4v pv;
          #pragma unroll
          for (int j=0;j<4;j++)
            pv[j] = f2bf((acc[mt][nt][4*g+j] + bv)*alpha);
          *(short4v*)&C[base + g*8 + hi*4] = pv;
        }
      } else {
        #pragma unroll
        for (int r=0;r<16;r++){
          const int grow = grow0 + (r&3) + 8*(r>>2) + 4*hi;
          C[(size_t)grow*512 + col] = f2bf((acc[mt][nt][r] + bv)*alpha);
        }
      }
    }
  }
}

// ---------------- fused flash attention v2 ----------------
// 256 blocks (b, 64-row q-tile) x 512 threads (8 waves). KVBLK=128.
// LDS: Q[64][512] swz (64KB) | ring 2x32KB | P^T[64][128] swz (16KB) | stats.
// S^T[kv][q]: wave (kvq=w>>1, qc=w&1) computes 32x32 subtile, contraction
// in 4 d-chunks of 128 streamed as K chunks [128kv][128d].
// PV: O^T[d][q], wave owns d-slice [64w,64w+64), V chunks [512d][32t].
#define Q_OFF    0
#define RING_OFF 65536
#define P_OFF    131072
#define PMAX_OFF 147456
#define LSUM_OFF 148480
#define ATTN_LDS 149504

__global__ __launch_bounds__(512, 2) void attn_fwd(
    const short* __restrict__ Qg, const short* __restrict__ Kg,
    const short* __restrict__ Vt, float* __restrict__ out)
{
  extern __shared__ char smem[];
  char*  ring     = smem + RING_OFF;
  float* pmax_lds = (float*)(smem + PMAX_OFF);
  float* lsum_lds = (float*)(smem + LSUM_OFF);

  const int tid = threadIdx.x;
  const int w = tid >> 6, lane = tid & 63;
  const int lo = lane & 31, hi = lane >> 5;
  const int kvq = w >> 1, qc = w & 1;
  const int b = blockIdx.x >> 6, qt = blockIdx.x & 63;
  const size_t qrow0 = ((size_t)b << 12) + (size_t)qt * 64;

  const char* Qb = (const char*)Qg;
  const char* Kb = (const char*)Kg;
  const char* Vb = (const char*)Vt;

  auto stageK = [&](char* dst, int t0, int c){
    #pragma unroll
    for (int i=0;i<4;i++){
      const int kvb = w*16 + i*4;                 // wave-uniform
      const int kv  = kvb + (lane>>4);
      const void* src = Kb + ((size_t)(b*4096 + t0 + kv))*1024 + c*256
                        + (((lane&15)*16) ^ ((kv&15)<<4));
      gl_lds16(src, dst + kvb*256);
    }
  };
  auto stageV = [&](char* dst, int t0, int tc){
    const char* base = Vb + ((size_t)(b*128 + (t0>>5) + tc))*32768;
    #pragma unroll
    for (int i=0;i<4;i++){
      const int db = w*64 + i*16;                 // wave-uniform
      const int d  = db + (lane>>2);
      const void* src = base + d*64 + (((lane&3)*16) ^ (((d>>1)&3)<<4));
      gl_lds16(src, dst + db*64);
    }
  };

  // ---- prologue: stage Q (swizzled source -> linear LDS) + K chunk 0 ----
  #pragma unroll
  for (int i=0;i<8;i++){
    const int q = w*8 + i;                        // wave-uniform
    const void* src = Qb + (qrow0 + q)*1024 + ((lane*16) ^ ((q&15)<<4));
    gl_lds16(src, smem + q*1024);
  }
  stageK(ring, 0, 0);

  f32x16 oacc[2][2];
  #pragma unroll
  for (int i=0;i<2;i++)
    #pragma unroll
    for (int j=0;j<2;j++)
      #pragma unroll
      for (int r=0;r<16;r++) oacc[i][j][r]=0.f;
  float m_run[2] = {-INFINITY, -INFINITY};
  float l_run[2] = {0.f, 0.f};

  __syncthreads();

  int slot = 0;
  const int swz = (lo&15)<<4;

  for (int t0 = 0; t0 < 4096; t0 += 128) {
    // ---- S phases: 4 K-chunks of 128 d ----
    f32x16 sacc;
    #pragma unroll
    for (int r=0;r<16;r++) sacc[r]=0.f;

    #pragma unroll
    for (int c=0;c<4;c++){
      if (c<3) stageK(ring + (slot^1)*32768, t0, c+1);
      else     stageV(ring + (slot^1)*32768, t0, 0);
      const char* kc = ring + slot*32768 + (kvq*32+lo)*256;
      const char* qb = smem + (qc*32+lo)*1024;
      #pragma unroll
      for (int dc=0;dc<8;dc++){
        const short8 kf = *(const short8*)(kc + ((dc*32 + hi*16) ^ swz));
        const short8 qf = *(const short8*)(qb + ((c*256 + dc*32 + hi*16) ^ swz));
        sacc = __builtin_amdgcn_mfma_f32_32x32x16_bf16(kf, qf, sacc, 0, 0, 0);
      }
      __syncthreads();
      slot ^= 1;
    }

    // ---- online softmax ----
    float px = sacc[0];
    #pragma unroll
    for (int r=1;r<16;r++) px = fmaxf(px, sacc[r]);
    px = fmaxf(px, __shfl_xor(px, 32));
    if (hi == 0) pmax_lds[w*32 + lo] = px;
    __syncthreads();                               // B1

    float m_new[2], resc[2];
    #pragma unroll
    for (int qq=0; qq<2; qq++){
      float mm = m_run[qq];
      #pragma unroll
      for (int kq=0; kq<4; kq++) mm = fmaxf(mm, pmax_lds[(kq*2+qq)*32 + lo]);
      m_new[qq] = mm;
      resc[qq] = exp2f((m_run[qq] - mm) * LOG2E);
      m_run[qq] = mm;
    }
    #pragma unroll
    for (int dt=0;dt<2;dt++)
      #pragma unroll
      for (int qq=0;qq<2;qq++)
        #pragma unroll
        for (int r=0;r<16;r++) oacc[dt][qq][r] *= resc[qq];

    float ls = 0.f;
    {
      const float mts = m_new[qc];
      char* prow = smem + P_OFF + (qc*32+lo)*256;
      #pragma unroll
      for (int g=0; g<4; g++){
        short4v pv;
        #pragma unroll
        for (int j=0;j<4;j++){
          const float p = exp2f((sacc[4*g+j] - mts) * LOG2E);
          ls += p;
          pv[j] = f2bf(p);
        }
        const int kv0 = kvq*32 + 8*g + 4*hi;       // row of reg 4g
        *(short4v*)(prow + ((kv0*2) ^ swz)) = pv;
      }
    }
    ls += __shfl_xor(ls, 32);
    if (hi == 0) lsum_lds[w*32 + lo] = ls;
    __syncthreads();                               // B2

    #pragma unroll
    for (int qq=0; qq<2; qq++){
      float s = 0.f;
      #pragma unroll
      for (int kq=0; kq<4; kq++) s += lsum_lds[(kq*2+qq)*32 + lo];
      l_run[qq] = l_run[qq]*resc[qq] + s;
    }

    // ---- PV phases: 4 V-chunks of 32 t ----
    #pragma unroll
    for (int tc=0;tc<4;tc++){
      if (tc<3) stageV(ring + (slot^1)*32768, t0, tc+1);
      else      stageK(ring + (slot^1)*32768, (t0+128)&4095, 0);
      const char* vcb = ring + slot*32768;
      short8 pf[2][2];
      #pragma unroll
      for (int q2=0;q2<2;q2++)
        #pragma unroll
        for (int ks=0;ks<2;ks++)
          pf[q2][ks] = *(const short8*)(smem + P_OFF + (q2*32+lo)*256
                          + ((tc*64 + ks*32 + hi*16) ^ swz));
      const int vswz = ((lo>>1)&3)<<4;
      #pragma unroll
      for (int dt=0;dt<2;dt++){
        const char* vrow = vcb + (w*64+dt*32+lo)*64;
        #pragma unroll
        for (int ks=0;ks<2;ks++){
          const short8 vf = *(const short8*)(vrow + ((ks*32 + hi*16) ^ vswz));
          oacc[dt][0] = __builtin_amdgcn_mfma_f32_32x32x16_bf16(vf, pf[0][ks], oacc[dt][0], 0, 0, 0);
          oacc[dt][1] = __builtin_amdgcn_mfma_f32_32x32x16_bf16(vf, pf[1][ks], oacc[dt][1], 0, 0, 0);
        }
      }
      __syncthreads();
      slot ^= 1;
    }
  }

  // ---- epilogue: out[q][d] = O^T[d][q] / l ----
  #pragma unroll
  for (int q2=0;q2<2;q2++){
    const float inv = 1.0f / l_run[q2];
    const size_t row = qrow0 + q2*32 + lo;
    #pragma unroll
    for (int dt=0;dt<2;dt++){
      #pragma unroll
      for (int g=0;g<4;g++){
        float4v ov;
        #pragma unroll
        for (int j=0;j<4;j++) ov[j] = oacc[dt][q2][4*g+j]*inv;
        *(float4v*)&out[row*512 + w*64 + dt*32 + g*8 + hi*4] = ov;
      }
    }
  }
}

extern "C" void kernel_launch(void* const* d_in, const int* in_sizes, int n_in,
                              void* d_out, int out_size, void* d_ws, size_t ws_size,
                              hipStream_t stream)
{
  const float* m_states = (const float*)d_in[0];
  const float* f_k      = (const float*)d_in[1];
  const float* f_v      = (const float*)d_in[2];
  const float* W_q      = (const float*)d_in[3];
  const float* b_q      = (const float*)d_in[4];
  const float* W_k      = (const float*)d_in[5];
  const float* b_k      = (const float*)d_in[6];
  const float* W_v      = (const float*)d_in[7];
  const float* b_v      = (const float*)d_in[8];
  float* out = (float*)d_out;

  // workspace: WqT 1MB | WkT 0.5MB | WvT 0.5MB | Qbf16 16MB | Kbf16 16MB | V^T 16MB
  char* ws = (char*)d_ws;
  short* WqT = (short*)(ws);
  short* WkT = (short*)(ws + 1048576);
  short* WvT = (short*)(ws + 1048576 + 524288);
  short* Qb  = (short*)(ws + 2097152);
  short* Kb  = Qb + (size_t)16384*512;
  short* VTw = Kb + (size_t)16384*512;

  transpose_cvt<<<2048, 256, 0, stream>>>(W_q, WqT, 10);
  transpose_cvt<<<1024, 256, 0, stream>>>(W_k, WkT, 9);
  transpose_cvt<<<1024, 256, 0, stream>>>(W_v, WvT, 9);

  const float scale = 0.044194173824159216f;   // 1/sqrt(512), folded into Q
  proj_gemm<0><<<dim3(128,4), 256, 0, stream>>>(m_states, WqT, b_q, Qb, 1024, scale);
  proj_gemm<0><<<dim3(128,4), 256, 0, stream>>>(f_k,      WkT, b_k, Kb,  512, 1.0f);
  proj_gemm<1><<<dim3(128,4), 256, 0, stream>>>(f_v,      WvT, b_v, VTw, 512, 1.0f);

  attn_fwd<<<256, 512, ATTN_LDS, stream>>>(Qb, Kb, VTw, out);
}

// Round 3
// 322.739 us; speedup vs baseline: 1.6698x; 1.0205x over previous
//
#include <hip/hip_runtime.h>

// ============================================================================
// InteractionLayer v3: Q/K/V projections (bf16 MFMA) + fused flash attention.
// All MFMA = v_mfma_f32_32x32x16_bf16.
//   a-operand: lane l holds A[row=l&31][k=(l>>5)*8 + j], j=0..7 (k-contiguous)
//   b-operand: lane l holds B[k=(l>>5)*8 + j][col=l&31] (= B^T row-major)
//   C/D:       col=lane&31, row=(reg&3)+8*(reg>>2)+4*(lane>>5)   [m74/m101]
// Attention v3: KVBLK=512, BQ=64, 8 waves. K/V stored FRAGMENT-TILED in ws and
// loaded direct global->reg (wave-private bands; coalesced 1KB frag loads,
// double-buffered). LDS only for shared data: Q resident (64KB, XOR-swizzled),
// P^[64q][512t] (64KB, XOR-swizzled), stats. 2 barriers per kv-tile.
// ============================================================================

typedef __attribute__((ext_vector_type(8)))  short short8;
typedef __attribute__((ext_vector_type(4)))  short short4v;
typedef __attribute__((ext_vector_type(16))) float f32x16;
typedef __attribute__((ext_vector_type(4)))  float float4v;

__device__ __forceinline__ short f2bf(float x){
  unsigned int u = __float_as_uint(x);
  u = (u + 0x7FFFu + ((u >> 16) & 1u)) >> 16;   // RNE f32->bf16 (finite inputs)
  return (short)u;
}

typedef const __attribute__((address_space(1))) unsigned int guint_t;
typedef __attribute__((address_space(3))) unsigned int luint_t;
__device__ __forceinline__ void gl_lds16(const void* g, void* l){
  __builtin_amdgcn_global_load_lds((guint_t*)g, (luint_t*)l, 16, 0, 0);
}

// ---------------- weight transpose + bf16 convert ----------------
__global__ __launch_bounds__(256) void transpose_cvt(
    const float* __restrict__ in, short* __restrict__ out, int kbits)
{
  int idx = blockIdx.x * 256 + threadIdx.x;
  int n = idx & 511;
  int k = idx >> 9;
  out[((size_t)n << kbits) + k] = f2bf(in[idx]);
}

// ---------------- projection GEMM ----------------
// C[16384,512] = A[16384,K]*W[K,512] + bias, then *alpha.
// MODE 0: C row-major bf16 [16384][512]                       (Q)
// MODE 2: K fragment-tiled: [t>>9][dchunk16][band16][ks2][lane64][16B]
//         frag elem: row=t&31, d=dchunk*32+ks*16+hi*8+j, lane=row+32*hi
// MODE 1: V fragment-tiled: [t>>9][tstep32][dband16][lane64][16B]
//         frag elem: row=d&31, t=tstep*16+hi*8+j, lane=row+32*hi
template<int MODE>
__global__ __launch_bounds__(256, 2) void proj_gemm(
    const float* __restrict__ A, const short* __restrict__ WT,
    const float* __restrict__ bias, short* __restrict__ C,
    int K, float alpha)
{
  __shared__ short As[128*72];
  __shared__ short Bs[128*72];
  const int tid = threadIdx.x;
  const int wid = tid >> 6, lane = tid & 63;
  const int lo = lane & 31, hi = lane >> 5;
  const int wm = wid >> 1, wn = wid & 1;
  const int bm = blockIdx.x, bn = blockIdx.y;

  f32x16 acc[2][2];
  #pragma unroll
  for (int i=0;i<2;i++)
    #pragma unroll
    for (int j=0;j<2;j++)
      #pragma unroll
      for (int r=0;r<16;r++) acc[i][j][r] = 0.0f;

  const int srow = tid >> 3, sslot = tid & 7;
  for (int k0 = 0; k0 < K; k0 += 64) {
    #pragma unroll
    for (int i=0;i<4;i++){
      const int row = srow + 32*i;
      const float4v* src = (const float4v*)&A[(size_t)(bm*128+row)*K + k0 + sslot*8];
      float4v f0 = src[0], f1 = src[1];
      short8 v;
      v[0]=f2bf(f0[0]); v[1]=f2bf(f0[1]); v[2]=f2bf(f0[2]); v[3]=f2bf(f0[3]);
      v[4]=f2bf(f1[0]); v[5]=f2bf(f1[1]); v[6]=f2bf(f1[2]); v[7]=f2bf(f1[3]);
      *(short8*)&As[row*72 + sslot*8] = v;
      *(short8*)&Bs[row*72 + sslot*8] =
          *(const short8*)&WT[(size_t)(bn*128+row)*K + k0 + sslot*8];
    }
    __syncthreads();
    #pragma unroll
    for (int dc=0; dc<4; dc++){
      short8 af[2], bfr[2];
      #pragma unroll
      for (int mt=0;mt<2;mt++)
        af[mt] = *(const short8*)&As[(wm*64+mt*32+lo)*72 + dc*16 + hi*8];
      #pragma unroll
      for (int nt=0;nt<2;nt++)
        bfr[nt] = *(const short8*)&Bs[(wn*64+nt*32+lo)*72 + dc*16 + hi*8];
      #pragma unroll
      for (int mt=0;mt<2;mt++)
        #pragma unroll
        for (int nt=0;nt<2;nt++)
          acc[mt][nt] = __builtin_amdgcn_mfma_f32_32x32x16_bf16(af[mt], bfr[nt], acc[mt][nt], 0, 0, 0);
    }
    __syncthreads();
  }

  char* Cb = (char*)C;
  #pragma unroll
  for (int nt=0;nt<2;nt++){
    const int col = bn*128 + wn*64 + nt*32 + lo;
    const float bv = bias[col];
    #pragma unroll
    for (int mt=0;mt<2;mt++){
      const int grow0 = bm*128 + wm*64 + mt*32;
      #pragma unroll
      for (int r=0;r<16;r++){
        const int t = grow0 + (r&3) + 8*(r>>2) + 4*hi;
        const int d = col;
        const float val = (acc[mt][nt][r] + bv) * alpha;
        if (MODE == 0){
          C[(size_t)t*512 + d] = f2bf(val);
        } else if (MODE == 2){   // K frag-tiled
          size_t addr = (size_t)(t>>9)*524288
                      + (size_t)((d>>5)*32 + ((t>>5)&15)*2 + ((d>>4)&1))*1024
                      + (size_t)((t&31) + 32*((d>>3)&1))*16 + (d&7)*2;
          *(short*)(Cb + addr) = f2bf(val);
        } else {                 // V frag-tiled
          size_t addr = (size_t)(t>>9)*524288
                      + (size_t)(((t>>4)&31)*16 + (d>>5))*1024
                      + (size_t)((d&31) + 32*((t>>3)&1))*16 + (t&7)*2;
          *(short*)(Cb + addr) = f2bf(val);
        }
      }
    }
  }
}

// ---------------- fused flash attention v3 ----------------
#define PLDS  65536
#define PMAXO 131072
#define LSUMO 133120
#define ALDS  135168

__global__ __launch_bounds__(512, 2) void attn_fwd(
    const char* __restrict__ Qg, const char* __restrict__ Kf,
    const char* __restrict__ Vf, float* __restrict__ out)
{
  extern __shared__ char smem[];
  float* pmax_lds = (float*)(smem + PMAXO);
  float* lsum_lds = (float*)(smem + LSUMO);

  const int tid = threadIdx.x;
  const int w = tid >> 6, lane = tid & 63;
  const int lo = lane & 31, hi = lane >> 5;
  const int wg = ((blockIdx.x & 7) << 5) + (blockIdx.x >> 3);  // XCD swizzle (256%8==0)
  const int b = wg >> 6, qt = wg & 63;
  const size_t qrow0 = ((size_t)b << 12) + (size_t)qt*64;
  const int swz = (lo & 15) << 4;

  // ---- prologue: stage Q resident (pre-swizzled source -> linear LDS) ----
  #pragma unroll
  for (int i=0;i<8;i++){
    const int q = w*8 + i;
    const void* src = Qg + (qrow0+q)*1024 + ((lane*16) ^ ((q&15)<<4));
    gl_lds16(src, smem + q*1024);
  }

  f32x16 oacc[2][2];
  #pragma unroll
  for (int i=0;i<2;i++)
    #pragma unroll
    for (int j=0;j<2;j++)
      #pragma unroll
      for (int r=0;r<16;r++) oacc[i][j][r]=0.f;
  float m_run[2] = {-INFINITY, -INFINITY};
  float l_run[2] = {0.f, 0.f};
  __syncthreads();

  const char* Kb = Kf + (size_t)b*4194304;
  const char* Vb = Vf + (size_t)b*4194304;

  for (int kvt = 0; kvt < 8; kvt++) {
    // ================= S phase: sacc[kvsub][qs] = K_band x Q =================
    // frag byte off = dchunk*32768 + (2w+kvsub)*2048 + ks*1024 + lane*16
    const char* kbase = Kb + (size_t)kvt*524288 + (size_t)(2*w)*2048 + (size_t)lane*16;
    f32x16 sacc[2][2];
    #pragma unroll
    for (int i=0;i<2;i++)
      #pragma unroll
      for (int j=0;j<2;j++)
        #pragma unroll
        for (int r=0;r<16;r++) sacc[i][j][r]=0.f;

    short8 kfb[2][8];
    #pragma unroll
    for (int kvsub=0;kvsub<2;kvsub++)
      #pragma unroll
      for (int dc2=0;dc2<2;dc2++)
        #pragma unroll
        for (int ks=0;ks<2;ks++)
          kfb[0][kvsub*4+dc2*2+ks] = *(const short8*)(kbase
              + (size_t)dc2*32768 + kvsub*2048 + ks*1024);

    #pragma unroll
    for (int g=0; g<8; g++){
      const int bf = g & 1;
      if (g < 7){
        #pragma unroll
        for (int kvsub=0;kvsub<2;kvsub++)
          #pragma unroll
          for (int dc2=0;dc2<2;dc2++)
            #pragma unroll
            for (int ks=0;ks<2;ks++)
              kfb[bf^1][kvsub*4+dc2*2+ks] = *(const short8*)(kbase
                  + (size_t)(2*(g+1)+dc2)*32768 + kvsub*2048 + ks*1024);
      }
      #pragma unroll
      for (int dc2=0;dc2<2;dc2++)
        #pragma unroll
        for (int ks=0;ks<2;ks++){
          const int dch = 2*g + dc2;
          short8 qf[2];
          #pragma unroll
          for (int qs=0;qs<2;qs++)
            qf[qs] = *(const short8*)(smem + (qs*32+lo)*1024
                       + ((dch*64 + ks*32 + hi*16) ^ swz));
          #pragma unroll
          for (int kvsub=0;kvsub<2;kvsub++)
            #pragma unroll
            for (int qs=0;qs<2;qs++)
              sacc[kvsub][qs] = __builtin_amdgcn_mfma_f32_32x32x16_bf16(
                  kfb[bf][kvsub*4+dc2*2+ks], qf[qs], sacc[kvsub][qs], 0, 0, 0);
        }
    }

    // ================= online softmax (base-2 domain; log2e folded in Q) ====
    float px[2];
    #pragma unroll
    for (int qs=0;qs<2;qs++){
      float p = sacc[0][qs][0];
      #pragma unroll
      for (int kvsub=0;kvsub<2;kvsub++)
        #pragma unroll
        for (int r=0;r<16;r++) p = fmaxf(p, sacc[kvsub][qs][r]);
      p = fmaxf(p, __shfl_xor(p, 32));
      px[qs] = p;
    }
    if (hi == 0){
      pmax_lds[w*64 + lo]      = px[0];
      pmax_lds[w*64 + 32 + lo] = px[1];
    }
    __syncthreads();                                   // B1

    float m_new[2], resc[2];
    #pragma unroll
    for (int qs=0;qs<2;qs++){
      float mm = m_run[qs];
      #pragma unroll
      for (int wv=0;wv<8;wv++) mm = fmaxf(mm, pmax_lds[wv*64 + qs*32 + lo]);
      m_new[qs] = mm;
      resc[qs] = exp2f(m_run[qs] - mm);
      m_run[qs] = mm;
    }
    #pragma unroll
    for (int ds=0;ds<2;ds++)
      #pragma unroll
      for (int qs=0;qs<2;qs++)
        #pragma unroll
        for (int r=0;r<16;r++) oacc[ds][qs][r] *= resc[qs];

    float ls[2] = {0.f, 0.f};
    #pragma unroll
    for (int kvsub=0;kvsub<2;kvsub++)
      #pragma unroll
      for (int qs=0;qs<2;qs++){
        char* prow = smem + PLDS + (qs*32+lo)*1024;
        #pragma unroll
        for (int g4=0; g4<4; g4++){
          short4v pv;
          #pragma unroll
          for (int j=0;j<4;j++){
            const float p = exp2f(sacc[kvsub][qs][4*g4+j] - m_new[qs]);
            ls[qs] += p;
            pv[j] = f2bf(p);
          }
          const int t0 = w*64 + kvsub*32 + 8*g4 + 4*hi;
          *(short4v*)(prow + ((t0*2) ^ swz)) = pv;
        }
      }
    ls[0] += __shfl_xor(ls[0], 32);
    ls[1] += __shfl_xor(ls[1], 32);
    if (hi == 0){
      lsum_lds[w*64 + lo]      = ls[0];
      lsum_lds[w*64 + 32 + lo] = ls[1];
    }
    __syncthreads();                                   // B2

    #pragma unroll
    for (int qs=0;qs<2;qs++){
      float s = 0.f;
      #pragma unroll
      for (int wv=0;wv<8;wv++) s += lsum_lds[wv*64 + qs*32 + lo];
      l_run[qs] = l_run[qs]*resc[qs] + s;
    }

    // ================= PV phase: oacc[dsub][qs] += V^T_band x P^ ============
    // frag byte off = tstep*16384 + (2w+dsub)*1024 + lane*16
    const char* vbase = Vb + (size_t)kvt*524288 + (size_t)(2*w)*1024 + (size_t)lane*16;
    short8 vfb[2][8];
    #pragma unroll
    for (int dsub=0;dsub<2;dsub++)
      #pragma unroll
      for (int ts=0;ts<4;ts++)
        vfb[0][dsub*4+ts] = *(const short8*)(vbase + (size_t)ts*16384 + dsub*1024);

    #pragma unroll
    for (int g=0; g<8; g++){
      const int bf = g & 1;
      if (g < 7){
        #pragma unroll
        for (int dsub=0;dsub<2;dsub++)
          #pragma unroll
          for (int ts=0;ts<4;ts++)
            vfb[bf^1][dsub*4+ts] = *(const short8*)(vbase
                + (size_t)((g+1)*4+ts)*16384 + dsub*1024);
      }
      #pragma unroll
      for (int ts=0; ts<4; ts++){
        const int tst = g*4 + ts;
        short8 pf[2];
        #pragma unroll
        for (int qs=0;qs<2;qs++)
          pf[qs] = *(const short8*)(smem + PLDS + (qs*32+lo)*1024
                     + ((tst*32 + hi*16) ^ swz));
        #pragma unroll
        for (int dsub=0;dsub<2;dsub++)
          #pragma unroll
          for (int qs=0;qs<2;qs++)
            oacc[dsub][qs] = __builtin_amdgcn_mfma_f32_32x32x16_bf16(
                vfb[bf][dsub*4+ts], pf[qs], oacc[dsub][qs], 0, 0, 0);
      }
    }
    // no barrier here: next tile's LDS writes are fenced by its B1/B2
  }

  // ---- epilogue: out[q][d] = O^T[d][q] / l ----
  #pragma unroll
  for (int qs=0;qs<2;qs++){
    const float inv = 1.0f / l_run[qs];
    const size_t row = qrow0 + qs*32 + lo;
    #pragma unroll
    for (int dsub=0;dsub<2;dsub++){
      #pragma unroll
      for (int g4=0;g4<4;g4++){
        float4v ov;
        #pragma unroll
        for (int j=0;j<4;j++) ov[j] = oacc[dsub][qs][4*g4+j]*inv;
        *(float4v*)&out[row*512 + w*64 + dsub*32 + g4*8 + hi*4] = ov;
      }
    }
  }
}

extern "C" void kernel_launch(void* const* d_in, const int* in_sizes, int n_in,
                              void* d_out, int out_size, void* d_ws, size_t ws_size,
                              hipStream_t stream)
{
  const float* m_states = (const float*)d_in[0];
  const float* f_k      = (const float*)d_in[1];
  const float* f_v      = (const float*)d_in[2];
  const float* W_q      = (const float*)d_in[3];
  const float* b_q      = (const float*)d_in[4];
  const float* W_k      = (const float*)d_in[5];
  const float* b_k      = (const float*)d_in[6];
  const float* W_v      = (const float*)d_in[7];
  const float* b_v      = (const float*)d_in[8];
  float* out = (float*)d_out;

  // workspace: WqT 1MB | WkT 0.5MB | WvT 0.5MB | Q 16MB | Kfrag 16MB | Vfrag 16MB
  char* ws = (char*)d_ws;
  short* WqT = (short*)(ws);
  short* WkT = (short*)(ws + 1048576);
  short* WvT = (short*)(ws + 1048576 + 524288);
  short* Qb  = (short*)(ws + 2097152);
  short* Kfr = Qb + (size_t)16384*512;
  short* Vfr = Kfr + (size_t)16384*512;

  transpose_cvt<<<2048, 256, 0, stream>>>(W_q, WqT, 10);
  transpose_cvt<<<1024, 256, 0, stream>>>(W_k, WkT, 9);
  transpose_cvt<<<1024, 256, 0, stream>>>(W_v, WvT, 9);

  // 1/sqrt(512) * log2(e): softmax runs in base-2 domain
  const float scale = 0.044194173824159216f * 1.4426950408889634f;
  proj_gemm<0><<<dim3(128,4), 256, 0, stream>>>(m_states, WqT, b_q, Qb, 1024, scale);
  proj_gemm<2><<<dim3(128,4), 256, 0, stream>>>(f_k,      WkT, b_k, Kfr,  512, 1.0f);
  proj_gemm<1><<<dim3(128,4), 256, 0, stream>>>(f_v,      WvT, b_v, Vfr,  512, 1.0f);

  attn_fwd<<<256, 512, ALDS, stream>>>((const char*)Qb, (const char*)Kfr,
                                       (const char*)Vfr, out);
}